// Round 1
// baseline (372.975 us; speedup 1.0000x reference)
//
#include <hip/hip_runtime.h>
#include <hip/hip_bf16.h>

// ws layout (floats):
//   [0..65]        partial max|w| (64 fc1 chunks, 1 conv, 1 fc2)
//   [128..202]     quantized w_conv (75)
//   [256..44159]   quantized w_fc1 TRANSPOSED [j=343][o=128]
//   [44160..44671] quantized w_fc2 [4][128]
#define WS_PARTIAL 0
#define WS_WCONV   128
#define WS_W1T     256
#define WS_W2      44160

__global__ __launch_bounds__(256) void quant_reduce(
    const float* __restrict__ wconv, const float* __restrict__ w1,
    const float* __restrict__ w2, float* __restrict__ ws) {
  __shared__ float red[256];
  int b = blockIdx.x, t = threadIdx.x;
  float m = 0.f;
  if (b < 64) {
    int base = b * 686;                       // 64 * 686 == 43904
    for (int i = t; i < 686; i += 256) m = fmaxf(m, fabsf(w1[base + i]));
  } else if (b == 64) {
    for (int i = t; i < 75; i += 256) m = fmaxf(m, fabsf(wconv[i]));
  } else {
    for (int i = t; i < 512; i += 256) m = fmaxf(m, fabsf(w2[i]));
  }
  red[t] = m;
  __syncthreads();
  for (int s = 128; s > 0; s >>= 1) {
    if (t < s) red[t] = fmaxf(red[t], red[t + s]);
    __syncthreads();
  }
  if (t == 0) ws[WS_PARTIAL + b] = red[0];
}

__device__ __forceinline__ float q4(float w, float s) {
  if (s <= 0.f) return 0.f;
  float r = rintf(w / s);                     // round-half-even == jnp.round
  r = fminf(fmaxf(r, -8.f), 7.f);
  return r * s;
}

__global__ __launch_bounds__(256) void quant_write(
    const float* __restrict__ wconv, const float* __restrict__ w1,
    const float* __restrict__ w2, float* __restrict__ ws) {
  int b = blockIdx.x, t = threadIdx.x;
  __shared__ float sS;
  if (b < 86) {                               // fc1: 86 blocks * 512 elems
    if (t == 0) {
      float m = ws[WS_PARTIAL];
      for (int i = 1; i < 64; ++i) m = fmaxf(m, ws[WS_PARTIAL + i]);
      sS = m * (1.0f / 7.0f);
    }
    __syncthreads();
    float s = sS;
    #pragma unroll
    for (int k = 0; k < 2; ++k) {
      int idx = b * 512 + k * 256 + t;
      if (idx < 43904) {
        float q = q4(w1[idx], s);
        int o = idx / 343;
        int j = idx - o * 343;
        ws[WS_W1T + j * 128 + o] = q;         // transpose for coalesced FC1
      }
    }
  } else if (b == 86) {
    float s = ws[WS_PARTIAL + 64] * (1.0f / 7.0f);
    if (t < 75) ws[WS_WCONV + t] = q4(wconv[t], s);
  } else {
    float s = ws[WS_PARTIAL + 65] * (1.0f / 7.0f);
    #pragma unroll
    for (int k = 0; k < 2; ++k) {
      int idx = k * 256 + t;
      ws[WS_W2 + idx] = q4(w2[idx], s);
    }
  }
}

// One block per batch element. x slice [31][16][31] staged in LDS with
// d-stride 500 (496 + 4 pad: keeps float4 16B alignment; spreads conv row
// banks to ~2-way aliasing, which is free per m136). Conv tasks (od,oh) = 196
// spread over all 4 waves (a wave0-only mapping would pin all conv FMAs to
// SIMD0 on every CU). Pooling merged via LDS atomicMax on order-preserving
// uint keys (kills the 11KB c1 buffer; static LDS stays under 64KB -> 2 blk/CU).
__global__ __launch_bounds__(256, 2) void fused_main(
    const float* __restrict__ x, const float* __restrict__ bconv,
    const float* __restrict__ bfc1, const float* __restrict__ bfc2,
    const float* __restrict__ ws, float* __restrict__ out) {
  __shared__ float xs[15496];                 // 30*500 + 15*31 + 31 = 15496
  __shared__ unsigned fkey[343];              // pooled features (keys -> float bits)
  __shared__ float fc1p[128];
  __shared__ float a1[128];
  __shared__ float s2[4];

  int b = blockIdx.x, t = threadIdx.x;

  // ---- phase 1: stage x[b] (float4, coalesced) + init pool keys ----
  {
    const float4* xb = (const float4*)(x + (size_t)b * 15376);
    for (int i = t; i < 3844; i += 256) {     // 15376/4
      float4 v = xb[i];
      int gi = i * 4;
      int d = gi / 496;                       // 496 = 16*31, divisible by 4
      int rem = gi - d * 496;
      *(float4*)&xs[d * 500 + rem] = v;
    }
    for (int i = t; i < 343; i += 256) fkey[i] = 0u;  // 0 < key(-inf)
  }
  __syncthreads();

  // ---- phase 2: conv (stride 2,1,2; kernel 5,3,5) + maxpool(2,2,2) ----
  if (t < 196) {
    int od = t / 14, oh = t - (t / 14) * 14;
    float acc[14];
    #pragma unroll
    for (int i = 0; i < 14; ++i) acc[i] = 0.f;
    const float* wq = ws + WS_WCONV;          // uniform indices -> s_load
    for (int kd = 0; kd < 5; ++kd) {
      for (int kh = 0; kh < 3; ++kh) {
        const float* r = &xs[(2 * od + kd) * 500 + (oh + kh) * 31];
        float row[31];
        #pragma unroll
        for (int i = 0; i < 31; ++i) row[i] = r[i];
        #pragma unroll
        for (int kw = 0; kw < 5; ++kw) {
          float wv = wq[(kd * 3 + kh) * 5 + kw];
          #pragma unroll
          for (int ow = 0; ow < 14; ++ow)
            acc[ow] = fmaf(row[2 * ow + kw], wv, acc[ow]);
        }
      }
    }
    int pd = od >> 1, ph = oh >> 1;
    #pragma unroll
    for (int pw = 0; pw < 7; ++pw) {
      float v = fmaxf(acc[2 * pw], acc[2 * pw + 1]);
      unsigned bb = __float_as_uint(v);
      unsigned key = (bb & 0x80000000u) ? ~bb : (bb | 0x80000000u);
      atomicMax(&fkey[pd * 49 + ph * 7 + pw], key);
    }
  }
  __syncthreads();

  // ---- phase 3: decode keys, add conv bias (max(conv)+b == max(conv+b)) ----
  {
    float bc = bconv[0];
    for (int i = t; i < 343; i += 256) {
      unsigned k = fkey[i];
      unsigned bb = (k & 0x80000000u) ? (k ^ 0x80000000u) : ~k;
      fkey[i] = __float_as_uint(__uint_as_float(bb) + bc);
    }
  }
  __syncthreads();

  // ---- phase 4: FC1 (343->128): 256 threads = 2 j-halves x 128 outputs ----
  int g = t >> 7, o = t & 127;
  float facc = 0.f;
  {
    const float* w1T = ws + WS_W1T;
    int j0 = g ? 172 : 0;
    int j1 = g ? 343 : 172;
    for (int j = j0; j < j1; ++j)
      facc = fmaf(__uint_as_float(fkey[j]), w1T[j * 128 + o], facc);
    if (g) fc1p[o] = facc;
  }
  __syncthreads();
  if (!g) {
    float v = facc + fc1p[o] + bfc1[o];
    a1[o] = fmaxf(v, 0.f);                    // ReLU
  }
  __syncthreads();

  // ---- phase 5: FC2 (128->4) + softmax ----
  if (t < 4) {
    const float* w2 = ws + WS_W2 + t * 128;
    float acc = bfc2[t];
    for (int k = 0; k < 128; ++k) acc = fmaf(a1[k], w2[k], acc);
    s2[t] = acc;
  }
  __syncthreads();
  if (t < 4) {
    float m = fmaxf(fmaxf(s2[0], s2[1]), fmaxf(s2[2], s2[3]));
    float e0 = expf(s2[0] - m), e1 = expf(s2[1] - m);
    float e2 = expf(s2[2] - m), e3 = expf(s2[3] - m);
    float inv = 1.f / (e0 + e1 + e2 + e3);
    float e = (t == 0) ? e0 : (t == 1) ? e1 : (t == 2) ? e2 : e3;
    out[b * 4 + t] = e * inv;
  }
}

extern "C" void kernel_launch(void* const* d_in, const int* in_sizes, int n_in,
                              void* d_out, int out_size, void* d_ws, size_t ws_size,
                              hipStream_t stream) {
  const float* x     = (const float*)d_in[0];
  const float* wconv = (const float*)d_in[1];
  const float* bconv = (const float*)d_in[2];
  const float* wfc1  = (const float*)d_in[3];
  const float* bfc1  = (const float*)d_in[4];
  const float* wfc2  = (const float*)d_in[5];
  const float* bfc2  = (const float*)d_in[6];
  float* out = (float*)d_out;
  float* ws  = (float*)d_ws;

  quant_reduce<<<66, 256, 0, stream>>>(wconv, wfc1, wfc2, ws);
  quant_write<<<88, 256, 0, stream>>>(wconv, wfc1, wfc2, ws);
  fused_main<<<2048, 256, 0, stream>>>(x, bconv, bfc1, bfc2, ws, out);
}

// Round 2
// 258.596 us; speedup vs baseline: 1.4423x; 1.4423x over previous
//
#include <hip/hip_runtime.h>
#include <hip/hip_bf16.h>

// ws layout (floats):
//   [0..65]          partial max|w| (64 fc1 chunks, 1 conv, 1 fc2)
//   [128..202]       quantized w_conv (75)
//   [256..44159]     quantized w_fc1 TRANSPOSED [j=343][o=128]
//   [44160..44671]   quantized w_fc2 [4][128]
//   [45056..747519]  pooled features [b=2048][343]  (2.81 MB)
#define WS_PARTIAL 0
#define WS_WCONV   128
#define WS_W1T     256
#define WS_W2      44160
#define WS_FEAT    45056

__global__ __launch_bounds__(256) void quant_reduce(
    const float* __restrict__ wconv, const float* __restrict__ w1,
    const float* __restrict__ w2, float* __restrict__ ws) {
  __shared__ float red[256];
  int b = blockIdx.x, t = threadIdx.x;
  float m = 0.f;
  if (b < 64) {
    int base = b * 686;                       // 64 * 686 == 43904
    for (int i = t; i < 686; i += 256) m = fmaxf(m, fabsf(w1[base + i]));
  } else if (b == 64) {
    for (int i = t; i < 75; i += 256) m = fmaxf(m, fabsf(wconv[i]));
  } else {
    for (int i = t; i < 512; i += 256) m = fmaxf(m, fabsf(w2[i]));
  }
  red[t] = m;
  __syncthreads();
  for (int s = 128; s > 0; s >>= 1) {
    if (t < s) red[t] = fmaxf(red[t], red[t + s]);
    __syncthreads();
  }
  if (t == 0) ws[WS_PARTIAL + b] = red[0];
}

__device__ __forceinline__ float q4(float w, float s) {
  if (s <= 0.f) return 0.f;
  float r = rintf(w / s);                     // round-half-even == jnp.round
  r = fminf(fmaxf(r, -8.f), 7.f);
  return r * s;
}

__global__ __launch_bounds__(256) void quant_write(
    const float* __restrict__ wconv, const float* __restrict__ w1,
    const float* __restrict__ w2, float* __restrict__ ws) {
  int b = blockIdx.x, t = threadIdx.x;
  __shared__ float sSs;
  if (b < 86) {                               // fc1: 86 blocks * 512 elems
    // parallel scale reduce (wave 0), not thread-0-serial
    float m = (t < 64) ? ws[WS_PARTIAL + t] : 0.f;
    #pragma unroll
    for (int off = 32; off; off >>= 1) m = fmaxf(m, __shfl_down(m, off));
    if (t == 0) sSs = m * (1.0f / 7.0f);
    __syncthreads();
    float s = sSs;
    #pragma unroll
    for (int k = 0; k < 2; ++k) {
      int idx = b * 512 + k * 256 + t;
      if (idx < 43904) {
        float q = q4(w1[idx], s);
        int o = idx / 343;
        int j = idx - o * 343;
        ws[WS_W1T + j * 128 + o] = q;         // transpose for coalesced FC1
      }
    }
  } else if (b == 86) {
    float s = ws[WS_PARTIAL + 64] * (1.0f / 7.0f);
    if (t < 75) ws[WS_WCONV + t] = q4(wconv[t], s);
  } else {
    float s = ws[WS_PARTIAL + 65] * (1.0f / 7.0f);
    #pragma unroll
    for (int k = 0; k < 2; ++k) {
      int idx = k * 256 + t;
      ws[WS_W2 + idx] = q4(w2[idx], s);
    }
  }
}

// Conv+pool: 2 blocks per batch (depth halves). LDS 38 KB -> 4 blocks/CU
// (16 waves, ~50% occupancy vs R1's 22%). One thread per pooled output:
// region loop over 7 input depths, 4x7 row window in regs, 8 conv accs,
// max-pool in regs, no atomics. Depth stride 500 in LDS (16B-aligned float4
// stores; pd-lane bank shift 16, ph shift 30 -> small mixed conflicts only).
__global__ __launch_bounds__(256, 4) void conv_pool(
    const float* __restrict__ x, const float* __restrict__ bconv,
    const float* __restrict__ ws, float* __restrict__ feat) {
  __shared__ float xs[9500];                  // 19 depths * 500
  int t = threadIdx.x;
  int half = blockIdx.x & 1;
  int b = blockIdx.x >> 1;
  int d0 = half ? 16 : 0;                     // staged depth range start
  int nfl4 = half ? 1860 : 2356;              // (15|19)*496/4 float4s

  const float4* src = (const float4*)(x + (size_t)b * 15376 + d0 * 496);
  for (int i = t; i < nfl4; i += 256) {
    float4 v = src[i];
    int gi = i * 4;
    int d = gi / 496;
    int rem = gi - d * 496;
    *(float4*)&xs[d * 500 + rem] = v;
  }
  __syncthreads();

  int npf = half ? 147 : 196;                 // pooled outputs this block
  if (t < npf) {
    int pdl = t / 49;                         // local pd (0..3 | 0..2)
    int rr = t - pdl * 49;
    int ph = rr / 7;
    int pw = rr - ph * 7;
    const float* wq = ws + WS_WCONV;          // uniform idx -> s_load
    float c[8];
    #pragma unroll
    for (int i = 0; i < 8; ++i) c[i] = 0.f;

    #pragma unroll
    for (int dd = 0; dd < 7; ++dd) {          // input depth offset in region
      float rg[4][7];
      const float* p = &xs[(4 * pdl + dd) * 500 + (2 * ph) * 31 + 4 * pw];
      #pragma unroll
      for (int hh = 0; hh < 4; ++hh)
        #pragma unroll
        for (int ww = 0; ww < 7; ++ww)
          rg[hh][ww] = p[hh * 31 + ww];
      #pragma unroll
      for (int odp = 0; odp < 2; ++odp) {     // od = 2*pd + odp
        int kd = dd - 2 * odp;
        if (kd < 0 || kd >= 5) continue;      // folds at compile time
        #pragma unroll
        for (int ohp = 0; ohp < 2; ++ohp)
          #pragma unroll
          for (int owp = 0; owp < 2; ++owp) {
            float a = c[odp * 4 + ohp * 2 + owp];
            #pragma unroll
            for (int kh = 0; kh < 3; ++kh)
              #pragma unroll
              for (int kw = 0; kw < 5; ++kw)
                a = fmaf(rg[ohp + kh][2 * owp + kw],
                         wq[kd * 15 + kh * 5 + kw], a);
            c[odp * 4 + ohp * 2 + owp] = a;
          }
      }
    }
    float m = c[0];
    #pragma unroll
    for (int i = 1; i < 8; ++i) m = fmaxf(m, c[i]);
    int pd = pdl + (half ? 4 : 0);
    feat[b * 343 + pd * 49 + rr] = m + bconv[0];  // coalesced per block
  }
}

// FC head: 4 batches per block; w1T element loaded once per block and fed to
// 4 FMAs (L2 traffic for w1T cut 4x vs batch-per-block). Features staged in
// LDS, read as same-address broadcast (conflict-free). Tiny LDS -> high occ.
__global__ __launch_bounds__(256) void fc_head(
    const float* __restrict__ ws, const float* __restrict__ bfc1,
    const float* __restrict__ bfc2, float* __restrict__ out) {
  __shared__ float fs[1372];                  // 4 * 343 features
  __shared__ float fc1p[4][128];
  __shared__ float a1s[4][128];
  __shared__ float s2[16];
  int t = threadIdx.x;
  int b0 = blockIdx.x * 4;

  const float4* fsrc = (const float4*)(ws + WS_FEAT + (size_t)b0 * 343);
  for (int i = t; i < 343; i += 256) ((float4*)fs)[i] = fsrc[i];
  __syncthreads();

  int g = t >> 7, o = t & 127;                // 2 j-halves x 128 outputs
  const float* w1T = ws + WS_W1T;
  float acc0 = 0.f, acc1 = 0.f, acc2 = 0.f, acc3 = 0.f;
  int j0 = g ? 172 : 0;
  int j1 = g ? 343 : 172;
  for (int j = j0; j < j1; ++j) {
    float w = w1T[j * 128 + o];               // coalesced, 512 B/wave
    acc0 = fmaf(fs[j], w, acc0);              // LDS broadcast reads
    acc1 = fmaf(fs[343 + j], w, acc1);
    acc2 = fmaf(fs[686 + j], w, acc2);
    acc3 = fmaf(fs[1029 + j], w, acc3);
  }
  if (g) {
    fc1p[0][o] = acc0; fc1p[1][o] = acc1;
    fc1p[2][o] = acc2; fc1p[3][o] = acc3;
  }
  __syncthreads();
  if (!g) {
    float bo = bfc1[o];
    a1s[0][o] = fmaxf(acc0 + fc1p[0][o] + bo, 0.f);
    a1s[1][o] = fmaxf(acc1 + fc1p[1][o] + bo, 0.f);
    a1s[2][o] = fmaxf(acc2 + fc1p[2][o] + bo, 0.f);
    a1s[3][o] = fmaxf(acc3 + fc1p[3][o] + bo, 0.f);
  }
  __syncthreads();
  if (t < 16) {
    int bb = t >> 2, cls = t & 3;
    const float* w2 = ws + WS_W2 + cls * 128;
    float a = bfc2[cls];
    for (int k = 0; k < 128; ++k) a = fmaf(a1s[bb][k], w2[k], a);
    s2[t] = a;
  }
  __syncthreads();
  if (t < 16) {
    int bb = t >> 2, cls = t & 3;
    float v0 = s2[bb * 4], v1 = s2[bb * 4 + 1];
    float v2 = s2[bb * 4 + 2], v3 = s2[bb * 4 + 3];
    float m = fmaxf(fmaxf(v0, v1), fmaxf(v2, v3));
    float e0 = expf(v0 - m), e1 = expf(v1 - m);
    float e2 = expf(v2 - m), e3 = expf(v3 - m);
    float inv = 1.f / (e0 + e1 + e2 + e3);
    float mine = (cls == 0) ? e0 : (cls == 1) ? e1 : (cls == 2) ? e2 : e3;
    out[(b0 + bb) * 4 + cls] = mine * inv;
  }
}

extern "C" void kernel_launch(void* const* d_in, const int* in_sizes, int n_in,
                              void* d_out, int out_size, void* d_ws, size_t ws_size,
                              hipStream_t stream) {
  const float* x     = (const float*)d_in[0];
  const float* wconv = (const float*)d_in[1];
  const float* bconv = (const float*)d_in[2];
  const float* wfc1  = (const float*)d_in[3];
  const float* bfc1  = (const float*)d_in[4];
  const float* wfc2  = (const float*)d_in[5];
  const float* bfc2  = (const float*)d_in[6];
  float* out = (float*)d_out;
  float* ws  = (float*)d_ws;

  quant_reduce<<<66, 256, 0, stream>>>(wconv, wfc1, wfc2, ws);
  quant_write<<<88, 256, 0, stream>>>(wconv, wfc1, wfc2, ws);
  conv_pool<<<4096, 256, 0, stream>>>(x, bconv, ws, ws + WS_FEAT);
  fc_head<<<512, 256, 0, stream>>>(ws, bfc1, bfc2, out);
}